// Round 7
// baseline (343.037 us; speedup 1.0000x reference)
//
#include <hip/hip_runtime.h>
#include <hip/hip_bf16.h>

typedef unsigned short us16;
typedef __attribute__((ext_vector_type(8))) short short8;   // 8 bf16 in 4 VGPRs
typedef __attribute__((ext_vector_type(4))) float float4v;  // MFMA C/D

#define E_DIM 1024
#define S_LEN 2048
#define B_DIM 2
#define H_DIM 16
#define HD_DIM 64
#define M_ROWS 4096
#define SCALE2 0.18033688011112042f  // (1/8) * log2(e), folded into Wcq/bcq

__device__ __forceinline__ float b2f(us16 b) {
    return __uint_as_float(((unsigned int)b) << 16);
}
__device__ __forceinline__ us16 f2b(float f) {           // RNE
    unsigned int u = __float_as_uint(f);
    unsigned int r = (u + 0x7fffu + ((u >> 16) & 1u)) >> 16;
    return (us16)r;
}

// async global->LDS, 16B/lane; lds base wave-uniform (HW adds lane*16)
__device__ __forceinline__ void gload16(const us16* g, us16* lds_uniform_base) {
    __builtin_amdgcn_global_load_lds(
        (const __attribute__((address_space(1))) void*)g,
        (__attribute__((address_space(3))) void*)lds_uniform_base, 16, 0, 0);
}

// ---------------------------------------------------------------------------
// prep: ALL preprocessing in one dispatch (12084 blocks x 256 thr).
// Mask pass is LDS-tiled: coalesced 128B global reads + coalesced 64B writes
// (old version did 32B reads at 8KB strides -> ~4x L2 overfetch, req-bound).
// ---------------------------------------------------------------------------
__global__ __launch_bounds__(256) void prep(
    const float* __restrict__ q, const float* __restrict__ k, const float* __restrict__ v,
    const float* __restrict__ Wq, const float* __restrict__ Wk, const float* __restrict__ Wv,
    const float* __restrict__ Whq, const float* __restrict__ Whk, const float* __restrict__ Whv,
    const float* __restrict__ Wo,
    const float* __restrict__ bq, const float* __restrict__ bk, const float* __restrict__ bv,
    const float* __restrict__ bhq, const float* __restrict__ bhk, const float* __restrict__ bhv,
    const int* __restrict__ mask,
    us16* qb, us16* kb, us16* vb, us16* Wqb, us16* Wkb, us16* Wvb,
    us16* WhqT, us16* WhkT, us16* WhvT, us16* WoT,
    us16* marr,
    float* bcq, float* bck, float* bcv, float* zbias)
{
    __shared__ us16 tile[32][33];
    __shared__ float red[4][64];
    __shared__ us16 Lm[128][72];     // mask window, padded rows
    int blk = blockIdx.x, tid = threadIdx.x;

    if (blk < 7680) {            // f32 -> bf16 streaming converts
        const float* in; us16* out; int idx;
        if (blk < 6144) {
            int z = blk >> 11, rem = blk & 2047;
            in = z == 0 ? q : z == 1 ? k : v;
            out = z == 0 ? qb : z == 1 ? kb : vb;
            idx = (rem * 256 + tid) * 8;
        } else {
            int t = blk - 6144, z = t >> 9, rem = t & 511;
            in = z == 0 ? Wq : z == 1 ? Wk : Wv;
            out = z == 0 ? Wqb : z == 1 ? Wkb : Wvb;
            idx = (rem * 256 + tid) * 8;
        }
        float4 f0 = *(const float4*)(in + idx);
        float4 f1 = *(const float4*)(in + idx + 4);
        us16 t8[8] = {f2b(f0.x), f2b(f0.y), f2b(f0.z), f2b(f0.w),
                      f2b(f1.x), f2b(f1.y), f2b(f1.z), f2b(f1.w)};
        *(uint4*)(out + idx) = *(const uint4*)t8;
    } else if (blk < 11776) {    // weight transposes
        int t = blk - 7680, z = t >> 10, rem = t & 1023;
        const float* in = z == 0 ? Whq : z == 1 ? Whk : z == 2 ? Whv : Wo;
        us16* out = z == 0 ? WhqT : z == 1 ? WhkT : z == 2 ? WhvT : WoT;
        int mode = (z < 3) ? 1 : 0;
        int bx = rem & 31, by = rem >> 5;
        int tx = tid & 31, ty = tid >> 5;
#pragma unroll
        for (int i = 0; i < 4; ++i) {
            int e = by * 32 + ty + i * 8;
            int c = bx * 32 + tx;
            size_t src;
            if (mode == 0) src = (size_t)e * E_DIM + c;
            else           src = ((size_t)(c >> 6) * E_DIM + e) * 64 + (c & 63);
            tile[ty + i * 8][tx] = f2b(in[src]);
        }
        __syncthreads();
#pragma unroll
        for (int i = 0; i < 4; ++i) {
            int c = bx * 32 + ty + i * 8;
            int e = by * 32 + tx;
            out[(size_t)c * E_DIM + e] = tile[tx][ty + i * 8];
        }
    } else if (blk < 12032) {    // mask -> additive-bias bf16 (LDS-tiled)
        // block = (bb, q0t, ktg); 4 kt per block; output layout UNCHANGED:
        // [b][kt:32][q0t:16][w:8][ld:2][lane:64][el:8]
        int t2 = blk - 11776;            // 0..255
        int ktg = t2 & 7, q0t2 = (t2 >> 3) & 15, bb = t2 >> 7;
        const us16 NEGB = f2b(-1e38f);
        for (int kk = 0; kk < 4; ++kk) {
            int kt = ktg * 4 + kk;
            __syncthreads();             // Lm reuse guard
            // stage 128 rows x 64 ints, coalesced (thread: 2 x 64B segments)
#pragma unroll
            for (int sgi = 0; sgi < 2; ++sgi) {
                int seg = tid * 2 + sgi;         // 0..511
                int row = seg >> 2, part = seg & 3;
                const int* mp = mask + ((size_t)bb * S_LEN + q0t2 * 128 + row) * S_LEN
                                + kt * 64 + part * 16;
                us16 tmp[16];
#pragma unroll
                for (int gi = 0; gi < 4; ++gi) {
                    int4 mv = *(const int4*)(mp + gi * 4);
                    tmp[gi * 4 + 0] = mv.x ? NEGB : (us16)0;
                    tmp[gi * 4 + 1] = mv.y ? NEGB : (us16)0;
                    tmp[gi * 4 + 2] = mv.z ? NEGB : (us16)0;
                    tmp[gi * 4 + 3] = mv.w ? NEGB : (us16)0;
                }
                *(uint4*)&Lm[row][part * 16]     = *(const uint4*)&tmp[0];
                *(uint4*)&Lm[row][part * 16 + 8] = *(const uint4*)&tmp[8];
            }
            __syncthreads();
            // emit: thread -> (w = tid>>5, ld = (tid>>4)&1, 4 lanes, 8 els)
            int wv2 = tid >> 5, ld2 = (tid >> 4) & 1, lb = (tid & 15) * 4;
            us16 obuf[32];
#pragma unroll
            for (int li = 0; li < 4; ++li) {
                int lane2 = lb + li;
                int row = wv2 * 16 + (lane2 & 15);
                int tb = ld2 * 32 + (lane2 >> 4) * 4;
                *(uint2*)&obuf[li * 8]     = *(const uint2*)&Lm[row][tb];
                *(uint2*)&obuf[li * 8 + 4] = *(const uint2*)&Lm[row][tb + 16];
            }
            size_t gbase = (((size_t)(bb * 32 + kt) * 16 + q0t2) * 8192) + (size_t)tid * 32;
#pragma unroll
            for (int gi = 0; gi < 4; ++gi)
                *(uint4*)&marr[gbase + gi * 8] = *(const uint4*)&obuf[gi * 8];
        }
    } else if (blk < 12080) {    // combined bias (Q-bias pre-scaled by SCALE2)
        int t = blk - 12032, z = t >> 4, h = t & 15;
        const float* bg = z == 0 ? bq : z == 1 ? bk : bv;
        const float* Wh = z == 0 ? Whq : z == 1 ? Whk : Whv;
        const float* bh = z == 0 ? bhq : z == 1 ? bhk : bhv;
        float* bc = z == 0 ? bcq : z == 1 ? bck : bcv;
        float sc = (z == 0) ? SCALE2 : 1.0f;
        int d = tid & 63, part = tid >> 6;
        float acc = 0.f;
        int j0 = part * 256;
        for (int j = j0; j < j0 + 256; ++j)
            acc += bg[j] * Wh[((size_t)h * E_DIM + j) * HD_DIM + d];
        red[part][d] = acc;
        __syncthreads();
        if (tid < 64)
            bc[h * 64 + tid] = (red[0][tid] + red[1][tid] + red[2][tid] + red[3][tid] + bh[h * 64 + tid]) * sc;
    } else {                     // zero zbias (4 blocks)
        int i = (blk - 12080) * 256 + tid;
        if (i < 1024) zbias[i] = 0.f;
    }
}

// ---------------------------------------------------------------------------
// GEMM body, 128x128x32 tile (all GEMMs now use this).
// omode 0: bf16 [M,N] (bias[col], *oscale); 1: bf16 [B,H,S,HD] (bias[col]);
// omode 2: f32 [M,N] (bias[col]);          3: bf16 [B,H,HD,S] (bias[row]).
// ---------------------------------------------------------------------------
#define BK 32

__device__ __forceinline__ void gemm_body(
    const us16* __restrict__ A, const us16* __restrict__ Bt,
    const float* __restrict__ bias, void* __restrict__ Cp,
    int M, int N, int K, int bxt, int byt, int omode, float oscale)
{
    __shared__ us16 As[128 * BK];
    __shared__ us16 Bs[128 * BK];

    int tid = threadIdx.x;
    int wave = tid >> 6, lane = tid & 63;
    int quad = lane >> 4, l16 = lane & 15;
    int wm = (wave >> 1) * 64, wn = (wave & 1) * 64;
    int bm0 = byt * 128, bn0 = bxt * 128;
    int srow = lane >> 2;
    int gcol = (((lane & 3) ^ (srow & 3)) << 3);
    int rslot = ((quad ^ (l16 & 3)) << 3);

    float4v acc[4][4];
#pragma unroll
    for (int i = 0; i < 4; ++i)
#pragma unroll
        for (int j = 0; j < 4; ++j)
#pragma unroll
            for (int r = 0; r < 4; ++r) acc[i][j][r] = 0.f;

    for (int k0 = 0; k0 < K; k0 += BK) {
#pragma unroll
        for (int c = 0; c < 2; ++c) {
            int r0 = 32 * wave + 16 * c;
            gload16(A  + (size_t)(bm0 + r0 + srow) * K + k0 + gcol, &As[r0 * BK]);
            gload16(Bt + (size_t)(bn0 + r0 + srow) * K + k0 + gcol, &Bs[r0 * BK]);
        }
        __syncthreads();
        short8 af[4], bfr[4];
#pragma unroll
        for (int i = 0; i < 4; ++i)
            af[i] = *(const short8*)&As[(wm + i * 16 + l16) * BK + rslot];
#pragma unroll
        for (int j = 0; j < 4; ++j)
            bfr[j] = *(const short8*)&Bs[(wn + j * 16 + l16) * BK + rslot];
#pragma unroll
        for (int i = 0; i < 4; ++i)
#pragma unroll
            for (int j = 0; j < 4; ++j)
                acc[i][j] = __builtin_amdgcn_mfma_f32_16x16x32_bf16(af[i], bfr[j], acc[i][j], 0, 0, 0);
        __syncthreads();
    }

#pragma unroll
    for (int i = 0; i < 4; ++i) {
#pragma unroll
        for (int j = 0; j < 4; ++j) {
#pragma unroll
            for (int r = 0; r < 4; ++r) {
                int row = bm0 + wm + i * 16 + quad * 4 + r;
                int col = bn0 + wn + j * 16 + l16;
                float vv = acc[i][j][r] + ((omode == 3) ? bias[row] : bias[col]);
                if (omode == 0) {
                    ((us16*)Cp)[(size_t)row * N + col] = f2b(vv * oscale);
                } else if (omode == 1) {
                    int b = row >> 11, s = row & 2047, h = col >> 6, d = col & 63;
                    ((us16*)Cp)[(((size_t)(b * H_DIM + h) * S_LEN + s) * HD_DIM) + d] = f2b(vv);
                } else if (omode == 2) {
                    ((float*)Cp)[(size_t)row * N + col] = vv;
                } else {  // 3: row=c (h*64+d), col=b*2048+s -> [B,H,HD,S]
                    int h = row >> 6, d = row & 63, b = col >> 11, sl = col & 2047;
                    ((us16*)Cp)[(((size_t)(b * H_DIM + h) * HD_DIM + d) * S_LEN) + sl] = f2b(vv);
                }
            }
        }
    }
}

// all three fused projections in ONE 768-block dispatch (3 blocks/CU)
__global__ __launch_bounds__(256) void proj_all(
    const us16* __restrict__ qb, const us16* __restrict__ kb, const us16* __restrict__ vb,
    const us16* __restrict__ WcqT, const us16* __restrict__ WckT, const us16* __restrict__ WcvT,
    const float* __restrict__ bcq, const float* __restrict__ bck, const float* __restrict__ bcv,
    us16* __restrict__ qhb, us16* __restrict__ khb, us16* __restrict__ vtb)
{
    int bx = blockIdx.x;
    int z = bx >> 8, t = bx & 255;
    if (z == 0)      gemm_body(qb, WcqT, bcq, qhb, M_ROWS, E_DIM, E_DIM, t & 7, t >> 3, 1, 1.0f);
    else if (z == 1) gemm_body(kb, WckT, bck, khb, M_ROWS, E_DIM, E_DIM, t & 7, t >> 3, 1, 1.0f);
    else             gemm_body(WcvT, vb, bcv, vtb, E_DIM, M_ROWS, E_DIM, t & 31, t >> 5, 3, 1.0f);
}

// batched weight-combine: C_z = WhT_z @ Wb_z^T; z==0 output pre-scaled SCALE2
// 128^2 tile, grid (8,8,3)
__global__ __launch_bounds__(256) void wgemm3(
    const us16* A0, const us16* A1, const us16* A2,
    const us16* B0, const us16* B1, const us16* B2,
    const float* zbias, us16* C0, us16* C1, us16* C2)
{
    int z = blockIdx.z;
    const us16* A = z == 0 ? A0 : z == 1 ? A1 : A2;
    const us16* Bt = z == 0 ? B0 : z == 1 ? B1 : B2;
    us16* C = z == 0 ? C0 : z == 1 ? C1 : C2;
    float sc = (z == 0) ? SCALE2 : 1.0f;
    gemm_body(A, Bt, zbias, C, E_DIM, E_DIM, E_DIM, blockIdx.x, blockIdx.y, 0, sc);
}

// out projection: f32 out, 128^2 tile, grid (8,32)
__global__ __launch_bounds__(256) void gemm_out(
    const us16* __restrict__ A, const us16* __restrict__ Bt,
    const float* __restrict__ bias, float* __restrict__ C, int M, int N, int K)
{
    gemm_body(A, Bt, bias, C, M, N, K, blockIdx.x, blockIdx.y, 2, 1.0f);
}

// ---------------------------------------------------------------------------
// Flash attention, S^T formulation (fixed-max softmax; scores pre-scaled via
// Wcq). Mask = bf16 additive bias (marr) as MFMA C-init; P via cvt_pk; l via
// ones-MFMA. Depth-2 pipeline with COUNTED vmcnt (T3/T4): per tile
//   SM(t) -> PV(t) -> barrier -> issue DMA(t+2) -> vmcnt(2) -> barrier
//   -> QK(t+1)
// FULL-S per block (no K-split): block = (bh, q0t), NT=32 K-tiles; O is
// finalized in-kernel (divide by l) and written straight to x -- no partials,
// no combine dispatch. Grid 512 blocks = exactly 2/CU, all co-resident.
// XCD-aware 1-D grid (4 heads/XCD). 512 thr = 8 waves, Q-tile 128.
// ---------------------------------------------------------------------------
#define PST 72   // Pw row stride (els)
#define NT 32    // K-tiles per block (64 wide, full S)

__global__ __launch_bounds__(512) void attn_kernel(
    const us16* __restrict__ qh, const us16* __restrict__ kh,
    const us16* __restrict__ vt, const us16* __restrict__ marr,
    us16* __restrict__ x)
{
    __shared__ us16 Ks[2][64 * 64];   // packed, swizzled: slot c holds chunk c^(t&7)
    __shared__ us16 Vs[2][64 * 64];
    __shared__ us16 Pw[8][16 * PST];

    int tid = threadIdx.x;
    int w = tid >> 6, lane = tid & 63;
    int quad = lane >> 4, l16 = lane & 15;

    // XCD-aware decode: 4 heads per XCD so K/V panels stay L2-resident.
    int wg = blockIdx.x;                 // 0..511
    int xcd = wg & 7, idx = wg >> 3;     // 64 blocks per XCD
    int bh = xcd * 4 + (idx >> 4);       // 4 bh per XCD
    int q0t = idx & 15;
    int q0 = q0t * 128;
    int b = bh >> 4;
    const size_t base = (size_t)bh * (S_LEN * HD_DIM);

    int qrow = q0 + w * 16 + l16;
    short8 qf0, qf1;
    {
        const us16* qp = qh + base + (size_t)qrow * HD_DIM + quad * 8;
        qf0 = *(const short8*)qp;
        qf1 = *(const short8*)(qp + 32);
    }

    // ones B-fragment for l = P x 1 (all bf16 1.0)
    short8 onesf;
#pragma unroll
    for (int j = 0; j < 8; ++j) onesf[j] = (short)0x3F80;

    // staging geometry: wave w stages rows w*8..w*8+7; slot c <- chunk c^(row&7)
    int strow = w * 8 + (lane >> 3);
    int scol = ((lane & 7) ^ (strow & 7)) * 8;
    const us16* ksrc0 = kh + base + (size_t)strow * HD_DIM + scol;
    const us16* vsrc0 = vt + base + (size_t)strow * S_LEN + scol;

    // mask-bias base: [b][kt:32][q0t:16][w:8][ld:2][lane:64][el:8]
    const us16* mb0p = marr + ((((size_t)(b * 32) * 16 + q0t) * 8 + w) * 1024)
                            + (size_t)lane * 8;

    // frag-read slots
    int slotA = (quad ^ (l16 & 7)) * 8;     // chunk quad
    int slotB = slotA ^ 32;                 // chunk quad+4

    float4v o[4];
#pragma unroll
    for (int dt = 0; dt < 4; ++dt)
#pragma unroll
        for (int r = 0; r < 4; ++r) o[dt][r] = 0.f;
    float4v o_l;
#pragma unroll
    for (int r = 0; r < 4; ++r) o_l[r] = 0.f;

    // QK for tile in KsC with mask C-init (m0,m1) -> sc[4]
    auto QK = [&](const us16* KsC, uint4 m0, uint4 m1, float4v* sc) {
        __builtin_amdgcn_s_setprio(1);
#pragma unroll
        for (int ct = 0; ct < 4; ++ct) {
            int tt = ct * 16 + l16;
            short8 kf0 = *(const short8*)&KsC[tt * 64 + slotA];
            short8 kf1 = *(const short8*)&KsC[tt * 64 + slotB];
            unsigned w0, w1;
            if (ct == 0)      { w0 = m0.x; w1 = m0.y; }
            else if (ct == 1) { w0 = m0.z; w1 = m0.w; }
            else if (ct == 2) { w0 = m1.x; w1 = m1.y; }
            else              { w0 = m1.z; w1 = m1.w; }
            float4v a;
            a[0] = __uint_as_float(w0 << 16);
            a[1] = __uint_as_float(w0 & 0xFFFF0000u);
            a[2] = __uint_as_float(w1 << 16);
            a[3] = __uint_as_float(w1 & 0xFFFF0000u);
            a = __builtin_amdgcn_mfma_f32_16x16x32_bf16(kf0, qf0, a, 0, 0, 0);
            a = __builtin_amdgcn_mfma_f32_16x16x32_bf16(kf1, qf1, a, 0, 0, 0);
            sc[ct] = a;
        }
        __builtin_amdgcn_s_setprio(0);
    };

    // prologue: stage tiles 0 and 1; mask(0); wait tile 0 only; QK(0)
    gload16(ksrc0, &Ks[0][w * 512]);
    gload16(vsrc0, &Vs[0][w * 512]);
    gload16(ksrc0 + (size_t)64 * HD_DIM, &Ks[1][w * 512]);
    gload16(vsrc0 + 64, &Vs[1][w * 512]);
    uint4 mc0 = *(const uint4*)(mb0p);
    uint4 mc1 = *(const uint4*)(mb0p + 512);
    asm volatile("s_waitcnt vmcnt(2)" ::: "memory");
    __builtin_amdgcn_s_barrier();
    __builtin_amdgcn_sched_barrier(0);

    float4v sc[4];
    QK(Ks[0], mc0, mc1, sc);

    for (int t = 0; t < NT; ++t) {
        int cur = t & 1;

        // mask(t+1) load early (hides under SM+PV)
        uint4 mn0 = mc0, mn1 = mc1;
        if (t + 1 < NT) {
            const us16* mp = mb0p + (size_t)(t + 1) * 131072;
            mn0 = *(const uint4*)(mp);
            mn1 = *(const uint4*)(mp + 512);
        }

        // SM(t): exp2 + cvt_pk pack + b64 write (scores pre-scaled via Wcq)
#pragma unroll
        for (int ct = 0; ct < 4; ++ct) {
            float p0 = __builtin_amdgcn_exp2f(sc[ct][0]);
            float p1 = __builtin_amdgcn_exp2f(sc[ct][1]);
            float p2 = __builtin_amdgcn_exp2f(sc[ct][2]);
            float p3 = __builtin_amdgcn_exp2f(sc[ct][3]);
            uint2 pk;
            asm("v_cvt_pk_bf16_f32 %0, %1, %2" : "=v"(pk.x) : "v"(p0), "v"(p1));
            asm("v_cvt_pk_bf16_f32 %0, %1, %2" : "=v"(pk.y) : "v"(p2), "v"(p3));
            *(uint2*)&Pw[w][l16 * PST + ct * 16 + quad * 4] = pk;
        }

        // PV(t): O += P.V ; l += P.1 (ones-MFMA)
        short8 pf0 = *(const short8*)&Pw[w][l16 * PST + quad * 8];
        short8 pf1 = *(const short8*)&Pw[w][l16 * PST + 32 + quad * 8];
        const us16* VsC = Vs[cur];
        __builtin_amdgcn_s_setprio(1);
#pragma unroll
        for (int dt = 0; dt < 4; ++dt) {
            int d = dt * 16 + l16;
            short8 vf0 = *(const short8*)&VsC[d * 64 + slotA];
            short8 vf1 = *(const short8*)&VsC[d * 64 + slotB];
            o[dt] = __builtin_amdgcn_mfma_f32_16x16x32_bf16(pf0, vf0, o[dt], 0, 0, 0);
            o[dt] = __builtin_amdgcn_mfma_f32_16x16x32_bf16(pf1, vf1, o[dt], 0, 0, 0);
        }
        o_l = __builtin_amdgcn_mfma_f32_16x16x32_bf16(pf0, onesf, o_l, 0, 0, 0);
        o_l = __builtin_amdgcn_mfma_f32_16x16x32_bf16(pf1, onesf, o_l, 0, 0, 0);
        __builtin_amdgcn_s_setprio(0);

        if (t + 1 == NT) break;

        // all waves done reading buf[cur] -> safe to overwrite
        __builtin_amdgcn_s_barrier();
        __builtin_amdgcn_sched_barrier(0);

        if (t + 2 < NT) {
            gload16(ksrc0 + (size_t)((t + 2) * 64) * HD_DIM, &Ks[cur][w * 512]);
            gload16(vsrc0 + (t + 2) * 64, &Vs[cur][w * 512]);
            // outstanding: DMA(t+1)=2 + DMA(t+2)=2; wait until only t+2 remains
            asm volatile("s_waitcnt vmcnt(2)" ::: "memory");
        } else {
            // nothing more to issue; drain DMA(t+1)
            asm volatile("s_waitcnt vmcnt(0)" ::: "memory");
        }
        __builtin_amdgcn_s_barrier();
        __builtin_amdgcn_sched_barrier(0);

        // QK(t+1) from the freshly-ready buffer
        mc0 = mn0; mc1 = mn1;
        QK(Ks[cur ^ 1], mc0, mc1, sc);
    }

    // finalize: divide by l (o_l[r] = row-sum, equal across l16) and write x
    float linv[4];
#pragma unroll
    for (int r = 0; r < 4; ++r) linv[r] = 1.0f / o_l[r];
    int h = bh & 15;
    int srow0 = q0 + w * 16 + quad * 4;
#pragma unroll
    for (int r = 0; r < 4; ++r) {
        size_t xro = ((size_t)(b * S_LEN + srow0 + r)) * E_DIM + h * HD_DIM;
#pragma unroll
        for (int dt = 0; dt < 4; ++dt)
            x[xro + dt * 16 + l16] = f2b(o[dt][r] * linv[r]);
    }
}

// ---------------------------------------------------------------------------
extern "C" void kernel_launch(void* const* d_in, const int* in_sizes, int n_in,
                              void* d_out, int out_size, void* d_ws, size_t ws_size,
                              hipStream_t stream) {
    const float* q    = (const float*)d_in[0];
    const float* k    = (const float*)d_in[1];
    const float* v    = (const float*)d_in[2];
    const int*   mask = (const int*)d_in[3];
    const float* Wq = (const float*)d_in[4];   const float* bq = (const float*)d_in[5];
    const float* Wk = (const float*)d_in[6];   const float* bk = (const float*)d_in[7];
    const float* Wv = (const float*)d_in[8];   const float* bv = (const float*)d_in[9];
    const float* Whq = (const float*)d_in[10]; const float* bhq = (const float*)d_in[11];
    const float* Whk = (const float*)d_in[12]; const float* bhk = (const float*)d_in[13];
    const float* Whv = (const float*)d_in[14]; const float* bhv = (const float*)d_in[15];
    const float* Wo = (const float*)d_in[16];  const float* bo = (const float*)d_in[17];

    us16* ws = (us16*)d_ws;
    const size_t M1 = (size_t)1 << 20;  // 1M bf16 elems = 2 MiB
    us16* WhqT = ws + 0 * M1;
    us16* WhkT = ws + 1 * M1;
    us16* WhvT = ws + 2 * M1;
    us16* WoT  = ws + 3 * M1;
    us16* WcqT = ws + 4 * M1;
    us16* WckT = ws + 5 * M1;
    us16* WcvT = ws + 6 * M1;
    us16* Wqb  = ws + 7 * M1;
    us16* Wkb  = ws + 8 * M1;
    us16* Wvb  = ws + 9 * M1;
    us16* qb   = ws + 10 * M1;   // 4M els each
    us16* kb   = ws + 14 * M1;
    us16* vb   = ws + 18 * M1;
    us16* qhb  = ws + 22 * M1;   // [B,H,S,HD]
    us16* khb  = ws + 26 * M1;
    us16* vtb  = ws + 30 * M1;   // [B,H,HD,S]
    us16* xb   = vb;             // vb dead after proj_all
    float* bcq   = (float*)(ws + 34 * M1);
    float* bck   = bcq + 1024;
    float* bcv   = bck + 1024;
    float* zbias = bcv + 1024;
    us16*  marr  = ws + 35 * M1;                         // 8M els = 16 MiB

    prep<<<12084, 256, 0, stream>>>(q, k, v, Wq, Wk, Wv, Whq, Whk, Whv, Wo,
                                    bq, bk, bv, bhq, bhk, bhv, mask,
                                    qb, kb, vb, Wqb, Wkb, Wvb,
                                    WhqT, WhkT, WhvT, WoT, marr,
                                    bcq, bck, bcv, zbias);

    // combined weights WcT[c][e] = sum_j Wh[h][j][d]*W[e][j] (Q pre-scaled)
    wgemm3<<<dim3(8, 8, 3), 256, 0, stream>>>(WhqT, WhkT, WhvT, Wqb, Wkb, Wvb, zbias,
                                              WcqT, WckT, WcvT);

    // all three projections in one 768-block dispatch
    proj_all<<<768, 256, 0, stream>>>(qb, kb, vb, WcqT, WckT, WcvT,
                                      bcq, bck, bcv, qhb, khb, vtb);

    // full-S flash attention, finalizes x in-kernel (no combine dispatch)
    attn_kernel<<<512, 512, 0, stream>>>(qhb, khb, vtb, marr, xb);

    // output projection, f32 out
    gemm_out<<<dim3(8, 32), 256, 0, stream>>>(xb, WoT, bo, (float*)d_out,
                                              M_ROWS, E_DIM, E_DIM);
}

// Round 8
// 310.232 us; speedup vs baseline: 1.1057x; 1.1057x over previous
//
#include <hip/hip_runtime.h>
#include <hip/hip_bf16.h>

typedef unsigned short us16;
typedef __attribute__((ext_vector_type(8))) short short8;   // 8 bf16 in 4 VGPRs
typedef __attribute__((ext_vector_type(4))) float float4v;  // MFMA C/D

#define E_DIM 1024
#define S_LEN 2048
#define B_DIM 2
#define H_DIM 16
#define HD_DIM 64
#define M_ROWS 4096
#define SCALE2 0.18033688011112042f  // (1/8) * log2(e), folded into Wcq/bcq

__device__ __forceinline__ float b2f(us16 b) {
    return __uint_as_float(((unsigned int)b) << 16);
}
__device__ __forceinline__ us16 f2b(float f) {           // RNE
    unsigned int u = __float_as_uint(f);
    unsigned int r = (u + 0x7fffu + ((u >> 16) & 1u)) >> 16;
    return (us16)r;
}

// async global->LDS, 16B/lane; lds base wave-uniform (HW adds lane*16)
__device__ __forceinline__ void gload16(const us16* g, us16* lds_uniform_base) {
    __builtin_amdgcn_global_load_lds(
        (const __attribute__((address_space(1))) void*)g,
        (__attribute__((address_space(3))) void*)lds_uniform_base, 16, 0, 0);
}

// ---------------------------------------------------------------------------
// prep: ALL preprocessing in one dispatch (12852 blocks x 256 thr).
// Mask packed to 64-bit ballots (mbits): fully coalesced reads, 1 MB output.
// ---------------------------------------------------------------------------
__global__ __launch_bounds__(256) void prep(
    const float* __restrict__ q, const float* __restrict__ k, const float* __restrict__ v,
    const float* __restrict__ Wq, const float* __restrict__ Wk, const float* __restrict__ Wv,
    const float* __restrict__ Whq, const float* __restrict__ Whk, const float* __restrict__ Whv,
    const float* __restrict__ Wo,
    const float* __restrict__ bq, const float* __restrict__ bk, const float* __restrict__ bv,
    const float* __restrict__ bhq, const float* __restrict__ bhk, const float* __restrict__ bhv,
    const int* __restrict__ mask,
    us16* qb, us16* kb, us16* vb, us16* Wqb, us16* Wkb, us16* Wvb,
    us16* WhqT, us16* WhkT, us16* WhvT, us16* WoT,
    unsigned long long* mbits,
    float* bcq, float* bck, float* bcv, float* zbias)
{
    __shared__ us16 tile[32][33];
    __shared__ float red[4][64];
    int blk = blockIdx.x, tid = threadIdx.x;

    if (blk < 7680) {            // f32 -> bf16 streaming converts
        const float* in; us16* out; int idx;
        if (blk < 6144) {
            int z = blk >> 11, rem = blk & 2047;
            in = z == 0 ? q : z == 1 ? k : v;
            out = z == 0 ? qb : z == 1 ? kb : vb;
            idx = (rem * 256 + tid) * 8;
        } else {
            int t = blk - 6144, z = t >> 9, rem = t & 511;
            in = z == 0 ? Wq : z == 1 ? Wk : Wv;
            out = z == 0 ? Wqb : z == 1 ? Wkb : Wvb;
            idx = (rem * 256 + tid) * 8;
        }
        float4 f0 = *(const float4*)(in + idx);
        float4 f1 = *(const float4*)(in + idx + 4);
        us16 t8[8] = {f2b(f0.x), f2b(f0.y), f2b(f0.z), f2b(f0.w),
                      f2b(f1.x), f2b(f1.y), f2b(f1.z), f2b(f1.w)};
        *(uint4*)(out + idx) = *(const uint4*)t8;
    } else if (blk < 11776) {    // weight transposes
        int t = blk - 7680, z = t >> 10, rem = t & 1023;
        const float* in = z == 0 ? Whq : z == 1 ? Whk : z == 2 ? Whv : Wo;
        us16* out = z == 0 ? WhqT : z == 1 ? WhkT : z == 2 ? WhvT : WoT;
        int mode = (z < 3) ? 1 : 0;
        int bx = rem & 31, by = rem >> 5;
        int tx = tid & 31, ty = tid >> 5;
#pragma unroll
        for (int i = 0; i < 4; ++i) {
            int e = by * 32 + ty + i * 8;
            int c = bx * 32 + tx;
            size_t src;
            if (mode == 0) src = (size_t)e * E_DIM + c;
            else           src = ((size_t)(c >> 6) * E_DIM + e) * 64 + (c & 63);
            tile[ty + i * 8][tx] = f2b(in[src]);
        }
        __syncthreads();
#pragma unroll
        for (int i = 0; i < 4; ++i) {
            int c = bx * 32 + ty + i * 8;
            int e = by * 32 + tx;
            out[(size_t)c * E_DIM + e] = tile[tx][ty + i * 8];
        }
    } else if (blk < 12800) {    // mask pack: 4 rows/block, one wave each
        int row = (blk - 11776) * 4 + (tid >> 6);
        int lane = tid & 63;
        const int* mp = mask + (size_t)row * S_LEN;
        for (int w = 0; w < 32; ++w) {
            int mv = mp[w * 64 + lane];
            unsigned long long bal = __ballot(mv != 0);
            if (lane == 0) mbits[(size_t)row * 32 + w] = bal;
        }
    } else if (blk < 12848) {    // combined bias (Q-bias pre-scaled by SCALE2)
        int t = blk - 12800, z = t >> 4, h = t & 15;
        const float* bg = z == 0 ? bq : z == 1 ? bk : bv;
        const float* Wh = z == 0 ? Whq : z == 1 ? Whk : Whv;
        const float* bh = z == 0 ? bhq : z == 1 ? bhk : bhv;
        float* bc = z == 0 ? bcq : z == 1 ? bck : bcv;
        float sc = (z == 0) ? SCALE2 : 1.0f;
        int d = tid & 63, part = tid >> 6;
        float acc = 0.f;
        int j0 = part * 256;
        for (int j = j0; j < j0 + 256; ++j)
            acc += bg[j] * Wh[((size_t)h * E_DIM + j) * HD_DIM + d];
        red[part][d] = acc;
        __syncthreads();
        if (tid < 64)
            bc[h * 64 + tid] = (red[0][tid] + red[1][tid] + red[2][tid] + red[3][tid] + bh[h * 64 + tid]) * sc;
    } else {                     // zero zbias (4 blocks)
        int i = (blk - 12848) * 256 + tid;
        if (i < 1024) zbias[i] = 0.f;
    }
}

// ---------------------------------------------------------------------------
// GEMM body, 128x128x32 tile (big batched projections).
// omode 1: bf16 [B,H,S,HD] (bias[col]); 3: bf16 [B,H,HD,S] (bias[row]).
// ---------------------------------------------------------------------------
#define BK 32

__device__ __forceinline__ void gemm_body(
    const us16* __restrict__ A, const us16* __restrict__ Bt,
    const float* __restrict__ bias, void* __restrict__ Cp,
    int M, int N, int K, int bxt, int byt, int omode)
{
    __shared__ us16 As[128 * BK];
    __shared__ us16 Bs[128 * BK];

    int tid = threadIdx.x;
    int wave = tid >> 6, lane = tid & 63;
    int quad = lane >> 4, l16 = lane & 15;
    int wm = (wave >> 1) * 64, wn = (wave & 1) * 64;
    int bm0 = byt * 128, bn0 = bxt * 128;
    int srow = lane >> 2;
    int gcol = (((lane & 3) ^ (srow & 3)) << 3);
    int rslot = ((quad ^ (l16 & 3)) << 3);

    float4v acc[4][4];
#pragma unroll
    for (int i = 0; i < 4; ++i)
#pragma unroll
        for (int j = 0; j < 4; ++j)
#pragma unroll
            for (int r = 0; r < 4; ++r) acc[i][j][r] = 0.f;

    for (int k0 = 0; k0 < K; k0 += BK) {
#pragma unroll
        for (int c = 0; c < 2; ++c) {
            int r0 = 32 * wave + 16 * c;
            gload16(A  + (size_t)(bm0 + r0 + srow) * K + k0 + gcol, &As[r0 * BK]);
            gload16(Bt + (size_t)(bn0 + r0 + srow) * K + k0 + gcol, &Bs[r0 * BK]);
        }
        __syncthreads();
        short8 af[4], bfr[4];
#pragma unroll
        for (int i = 0; i < 4; ++i)
            af[i] = *(const short8*)&As[(wm + i * 16 + l16) * BK + rslot];
#pragma unroll
        for (int j = 0; j < 4; ++j)
            bfr[j] = *(const short8*)&Bs[(wn + j * 16 + l16) * BK + rslot];
#pragma unroll
        for (int i = 0; i < 4; ++i)
#pragma unroll
            for (int j = 0; j < 4; ++j)
                acc[i][j] = __builtin_amdgcn_mfma_f32_16x16x32_bf16(af[i], bfr[j], acc[i][j], 0, 0, 0);
        __syncthreads();
    }

#pragma unroll
    for (int i = 0; i < 4; ++i) {
#pragma unroll
        for (int j = 0; j < 4; ++j) {
#pragma unroll
            for (int r = 0; r < 4; ++r) {
                int row = bm0 + wm + i * 16 + quad * 4 + r;
                int col = bn0 + wn + j * 16 + l16;
                float vv = acc[i][j][r] + ((omode == 3) ? bias[row] : bias[col]);
                if (omode == 1) {
                    int b = row >> 11, s = row & 2047, h = col >> 6, d = col & 63;
                    ((us16*)Cp)[(((size_t)(b * H_DIM + h) * S_LEN + s) * HD_DIM) + d] = f2b(vv);
                } else {  // 3: row=c (h*64+d), col=b*2048+s -> [B,H,HD,S]
                    int h = row >> 6, d = row & 63, b = col >> 11, sl = col & 2047;
                    ((us16*)Cp)[(((size_t)(b * H_DIM + h) * HD_DIM + d) * S_LEN) + sl] = f2b(vv);
                }
            }
        }
    }
}

// all three fused projections in ONE 768-block dispatch (3 blocks/CU)
__global__ __launch_bounds__(256) void proj_all(
    const us16* __restrict__ qb, const us16* __restrict__ kb, const us16* __restrict__ vb,
    const us16* __restrict__ WcqT, const us16* __restrict__ WckT, const us16* __restrict__ WcvT,
    const float* __restrict__ bcq, const float* __restrict__ bck, const float* __restrict__ bcv,
    us16* __restrict__ qhb, us16* __restrict__ khb, us16* __restrict__ vtb)
{
    int bx = blockIdx.x;
    int z = bx >> 8, t = bx & 255;
    if (z == 0)      gemm_body(qb, WcqT, bcq, qhb, M_ROWS, E_DIM, E_DIM, t & 7, t >> 3, 1);
    else if (z == 1) gemm_body(kb, WckT, bck, khb, M_ROWS, E_DIM, E_DIM, t & 7, t >> 3, 1);
    else             gemm_body(WcvT, vb, bcv, vtb, E_DIM, M_ROWS, E_DIM, t & 31, t >> 5, 3);
}

// ---------------------------------------------------------------------------
// 64x128-tile GEMM body. OMODE 0: bf16 [M,N]; 2: f32 [M,N]. bias[col], *oscale.
// ---------------------------------------------------------------------------
template<int OMODE>
__device__ __forceinline__ void gemm64_body(
    const us16* __restrict__ A, const us16* __restrict__ Bt,
    const float* __restrict__ bias, void* __restrict__ Cp,
    int M, int N, int K, int bxt, int byt, float oscale)
{
    __shared__ us16 As[64 * BK];
    __shared__ us16 Bs[128 * BK];

    int tid = threadIdx.x;
    int wave = tid >> 6, lane = tid & 63;
    int quad = lane >> 4, l16 = lane & 15;
    int wm = (wave >> 1) * 32, wn = (wave & 1) * 64;
    int bm0 = byt * 64, bn0 = bxt * 128;
    int srow = lane >> 2;
    int gcol = (((lane & 3) ^ (srow & 3)) << 3);
    int rslot = ((quad ^ (l16 & 3)) << 3);

    float4v acc[2][4];
#pragma unroll
    for (int i = 0; i < 2; ++i)
#pragma unroll
        for (int j = 0; j < 4; ++j)
#pragma unroll
            for (int r = 0; r < 4; ++r) acc[i][j][r] = 0.f;

    for (int k0 = 0; k0 < K; k0 += BK) {
        gload16(A + (size_t)(bm0 + 16 * wave + srow) * K + k0 + gcol, &As[16 * wave * BK]);
#pragma unroll
        for (int c = 0; c < 2; ++c) {
            int r0 = 32 * wave + 16 * c;
            gload16(Bt + (size_t)(bn0 + r0 + srow) * K + k0 + gcol, &Bs[r0 * BK]);
        }
        __syncthreads();
        short8 af[2], bfr[4];
#pragma unroll
        for (int i = 0; i < 2; ++i)
            af[i] = *(const short8*)&As[(wm + i * 16 + l16) * BK + rslot];
#pragma unroll
        for (int j = 0; j < 4; ++j)
            bfr[j] = *(const short8*)&Bs[(wn + j * 16 + l16) * BK + rslot];
#pragma unroll
        for (int i = 0; i < 2; ++i)
#pragma unroll
            for (int j = 0; j < 4; ++j)
                acc[i][j] = __builtin_amdgcn_mfma_f32_16x16x32_bf16(af[i], bfr[j], acc[i][j], 0, 0, 0);
        __syncthreads();
    }

#pragma unroll
    for (int i = 0; i < 2; ++i)
#pragma unroll
        for (int j = 0; j < 4; ++j)
#pragma unroll
            for (int r = 0; r < 4; ++r) {
                int row = bm0 + wm + i * 16 + quad * 4 + r;
                int col = bn0 + wn + j * 16 + l16;
                float vv = (acc[i][j][r] + bias[col]) * oscale;
                if (OMODE == 0) ((us16*)Cp)[(size_t)row * N + col] = f2b(vv);
                else            ((float*)Cp)[(size_t)row * N + col] = vv;
            }
}

// batched weight-combine: C_z = WhT_z @ Wb_z^T; z==0 output pre-scaled SCALE2
__global__ __launch_bounds__(256) void wgemm3(
    const us16* A0, const us16* A1, const us16* A2,
    const us16* B0, const us16* B1, const us16* B2,
    const float* zbias, us16* C0, us16* C1, us16* C2)
{
    int z = blockIdx.z;
    const us16* A = z == 0 ? A0 : z == 1 ? A1 : A2;
    const us16* Bt = z == 0 ? B0 : z == 1 ? B1 : B2;
    us16* C = z == 0 ? C0 : z == 1 ? C1 : C2;
    float sc = (z == 0) ? SCALE2 : 1.0f;
    gemm64_body<0>(A, Bt, zbias, C, E_DIM, E_DIM, E_DIM, blockIdx.x, blockIdx.y, sc);
}

// out projection: f32 out, grid (8,64)=512 blocks
__global__ __launch_bounds__(256) void gemm_out64(
    const us16* __restrict__ A, const us16* __restrict__ Bt,
    const float* __restrict__ bias, float* __restrict__ C, int M, int N, int K)
{
    gemm64_body<2>(A, Bt, bias, C, M, N, K, blockIdx.x, blockIdx.y, 1.0f);
}

// ---------------------------------------------------------------------------
// Flash attention, S^T formulation (fixed-max softmax; scores pre-scaled via
// Wcq). Mask = 64-bit ballots (mbits), expanded to the MFMA C-initializer:
// a[r] = bit ? -1e38 : 0 (bit index t = ct*16 + quad*4 + r, round-2-verified).
// P via cvt_pk; l via ones-MFMA. Depth-2 pipeline with COUNTED vmcnt:
//   SM(t) -> PV(t) -> barrier -> issue DMA(t+2) -> vmcnt(2) -> barrier
//   -> QK(t+1)
// FULL-S per block: block = (bh, q0t), NT=32 K-tiles; O finalized in-kernel
// (divide by l), written straight to x. Grid 512 = 2/CU, all co-resident.
// XCD-aware 1-D grid (4 heads/XCD). 512 thr = 8 waves, Q-tile 128.
// ---------------------------------------------------------------------------
#define PST 72   // Pw row stride (els)
#define NT 32    // K-tiles per block (64 wide, full S)

__global__ __launch_bounds__(512) void attn_kernel(
    const us16* __restrict__ qh, const us16* __restrict__ kh,
    const us16* __restrict__ vt, const unsigned long long* __restrict__ mbits,
    us16* __restrict__ x)
{
    __shared__ us16 Ks[2][64 * 64];   // packed, swizzled: slot c holds chunk c^(t&7)
    __shared__ us16 Vs[2][64 * 64];
    __shared__ us16 Pw[8][16 * PST];

    int tid = threadIdx.x;
    int w = tid >> 6, lane = tid & 63;
    int quad = lane >> 4, l16 = lane & 15;

    // XCD-aware decode: 4 heads per XCD so K/V panels stay L2-resident.
    int wg = blockIdx.x;                 // 0..511
    int xcd = wg & 7, idx = wg >> 3;     // 64 blocks per XCD
    int bh = xcd * 4 + (idx >> 4);       // 4 bh per XCD
    int q0t = idx & 15;
    int q0 = q0t * 128;
    int b = bh >> 4;
    const size_t base = (size_t)bh * (S_LEN * HD_DIM);

    int qrow = q0 + w * 16 + l16;
    short8 qf0, qf1;
    {
        const us16* qp = qh + base + (size_t)qrow * HD_DIM + quad * 8;
        qf0 = *(const short8*)qp;
        qf1 = *(const short8*)(qp + 32);
    }

    // ones B-fragment for l = P x 1 (all bf16 1.0)
    short8 onesf;
#pragma unroll
    for (int j = 0; j < 8; ++j) onesf[j] = (short)0x3F80;

    // staging geometry: wave w stages rows w*8..w*8+7; slot c <- chunk c^(row&7)
    int strow = w * 8 + (lane >> 3);
    int scol = ((lane & 7) ^ (strow & 7)) * 8;
    const us16* ksrc0 = kh + base + (size_t)strow * HD_DIM + scol;
    const us16* vsrc0 = vt + base + (size_t)strow * S_LEN + scol;

    // per-lane mask row: 32 x 64-bit words (one per K-tile)
    const unsigned long long* mrow = mbits + ((size_t)(b * S_LEN + qrow) * 32);

    // frag-read slots
    int slotA = (quad ^ (l16 & 7)) * 8;     // chunk quad
    int slotB = slotA ^ 32;                 // chunk quad+4

    float4v o[4];
#pragma unroll
    for (int dt = 0; dt < 4; ++dt)
#pragma unroll
        for (int r = 0; r < 4; ++r) o[dt][r] = 0.f;
    float4v o_l;
#pragma unroll
    for (int r = 0; r < 4; ++r) o_l[r] = 0.f;

    // QK for tile in KsC; mask bits -> C-init (bit t = ct*16 + quad*4 + r)
    auto QK = [&](const us16* KsC, unsigned long long mw, float4v* sc) {
        __builtin_amdgcn_s_setprio(1);
#pragma unroll
        for (int ct = 0; ct < 4; ++ct) {
            int tt = ct * 16 + l16;
            short8 kf0 = *(const short8*)&KsC[tt * 64 + slotA];
            short8 kf1 = *(const short8*)&KsC[tt * 64 + slotB];
            unsigned bits = (unsigned)(mw >> (ct * 16 + quad * 4));
            float4v a;
            a[0] = (bits & 1u) ? -1e38f : 0.f;
            a[1] = (bits & 2u) ? -1e38f : 0.f;
            a[2] = (bits & 4u) ? -1e38f : 0.f;
            a[3] = (bits & 8u) ? -1e38f : 0.f;
            a = __builtin_amdgcn_mfma_f32_16x16x32_bf16(kf0, qf0, a, 0, 0, 0);
            a = __builtin_amdgcn_mfma_f32_16x16x32_bf16(kf1, qf1, a, 0, 0, 0);
            sc[ct] = a;
        }
        __builtin_amdgcn_s_setprio(0);
    };

    // prologue: stage tiles 0 and 1; mask word 0; wait tile 0 only; QK(0)
    gload16(ksrc0, &Ks[0][w * 512]);
    gload16(vsrc0, &Vs[0][w * 512]);
    gload16(ksrc0 + (size_t)64 * HD_DIM, &Ks[1][w * 512]);
    gload16(vsrc0 + 64, &Vs[1][w * 512]);
    unsigned long long mw = mrow[0];
    asm volatile("s_waitcnt vmcnt(2)" ::: "memory");
    __builtin_amdgcn_s_barrier();
    __builtin_amdgcn_sched_barrier(0);

    float4v sc[4];
    QK(Ks[0], mw, sc);

    for (int t = 0; t < NT; ++t) {
        int cur = t & 1;

        // mask word (t+1) load early (hides under SM+PV)
        unsigned long long mwn = 0ull;
        if (t + 1 < NT) mwn = mrow[t + 1];

        // SM(t): exp2 + cvt_pk pack + b64 write (scores pre-scaled via Wcq)
#pragma unroll
        for (int ct = 0; ct < 4; ++ct) {
            float p0 = __builtin_amdgcn_exp2f(sc[ct][0]);
            float p1 = __builtin_amdgcn_exp2f(sc[ct][1]);
            float p2 = __builtin_amdgcn_exp2f(sc[ct][2]);
            float p3 = __builtin_amdgcn_exp2f(sc[ct][3]);
            uint2 pk;
            asm("v_cvt_pk_bf16_f32 %0, %1, %2" : "=v"(pk.x) : "v"(p0), "v"(p1));
            asm("v_cvt_pk_bf16_f32 %0, %1, %2" : "=v"(pk.y) : "v"(p2), "v"(p3));
            *(uint2*)&Pw[w][l16 * PST + ct * 16 + quad * 4] = pk;
        }

        // PV(t): O += P.V ; l += P.1 (ones-MFMA)
        short8 pf0 = *(const short8*)&Pw[w][l16 * PST + quad * 8];
        short8 pf1 = *(const short8*)&Pw[w][l16 * PST + 32 + quad * 8];
        const us16* VsC = Vs[cur];
        __builtin_amdgcn_s_setprio(1);
#pragma unroll
        for (int dt = 0; dt < 4; ++dt) {
            int d = dt * 16 + l16;
            short8 vf0 = *(const short8*)&VsC[d * 64 + slotA];
            short8 vf1 = *(const short8*)&VsC[d * 64 + slotB];
            o[dt] = __builtin_amdgcn_mfma_f32_16x16x32_bf16(pf0, vf0, o[dt], 0, 0, 0);
            o[dt] = __builtin_amdgcn_mfma_f32_16x16x32_bf16(pf1, vf1, o[dt], 0, 0, 0);
        }
        o_l = __builtin_amdgcn_mfma_f32_16x16x32_bf16(pf0, onesf, o_l, 0, 0, 0);
        o_l = __builtin_amdgcn_mfma_f32_16x16x32_bf16(pf1, onesf, o_l, 0, 0, 0);
        __builtin_amdgcn_s_setprio(0);

        if (t + 1 == NT) break;

        // all waves done reading buf[cur] -> safe to overwrite
        __builtin_amdgcn_s_barrier();
        __builtin_amdgcn_sched_barrier(0);

        if (t + 2 < NT) {
            gload16(ksrc0 + (size_t)((t + 2) * 64) * HD_DIM, &Ks[cur][w * 512]);
            gload16(vsrc0 + (t + 2) * 64, &Vs[cur][w * 512]);
            // outstanding: DMA(t+1)=2 + DMA(t+2)=2; wait until only t+2 remains
            asm volatile("s_waitcnt vmcnt(2)" ::: "memory");
        } else {
            // nothing more to issue; drain DMA(t+1)
            asm volatile("s_waitcnt vmcnt(0)" ::: "memory");
        }
        __builtin_amdgcn_s_barrier();
        __builtin_amdgcn_sched_barrier(0);

        // QK(t+1) from the freshly-ready buffer
        mw = mwn;
        QK(Ks[cur ^ 1], mw, sc);
    }

    // finalize: divide by l (o_l[r] = row-sum, equal across l16) and write x
    float linv[4];
#pragma unroll
    for (int r = 0; r < 4; ++r) linv[r] = 1.0f / o_l[r];
    int h = bh & 15;
    int srow0 = q0 + w * 16 + quad * 4;
#pragma unroll
    for (int r = 0; r < 4; ++r) {
        size_t xro = ((size_t)(b * S_LEN + srow0 + r)) * E_DIM + h * HD_DIM;
#pragma unroll
        for (int dt = 0; dt < 4; ++dt)
            x[xro + dt * 16 + l16] = f2b(o[dt][r] * linv[r]);
    }
}

// ---------------------------------------------------------------------------
extern "C" void kernel_launch(void* const* d_in, const int* in_sizes, int n_in,
                              void* d_out, int out_size, void* d_ws, size_t ws_size,
                              hipStream_t stream) {
    const float* q    = (const float*)d_in[0];
    const float* k    = (const float*)d_in[1];
    const float* v    = (const float*)d_in[2];
    const int*   mask = (const int*)d_in[3];
    const float* Wq = (const float*)d_in[4];   const float* bq = (const float*)d_in[5];
    const float* Wk = (const float*)d_in[6];   const float* bk = (const float*)d_in[7];
    const float* Wv = (const float*)d_in[8];   const float* bv = (const float*)d_in[9];
    const float* Whq = (const float*)d_in[10]; const float* bhq = (const float*)d_in[11];
    const float* Whk = (const float*)d_in[12]; const float* bhk = (const float*)d_in[13];
    const float* Whv = (const float*)d_in[14]; const float* bhv = (const float*)d_in[15];
    const float* Wo = (const float*)d_in[16];  const float* bo = (const float*)d_in[17];

    us16* ws = (us16*)d_ws;
    const size_t M1 = (size_t)1 << 20;  // 1M bf16 elems = 2 MiB
    us16* WhqT = ws + 0 * M1;
    us16* WhkT = ws + 1 * M1;
    us16* WhvT = ws + 2 * M1;
    us16* WoT  = ws + 3 * M1;
    us16* WcqT = ws + 4 * M1;
    us16* WckT = ws + 5 * M1;
    us16* WcvT = ws + 6 * M1;
    us16* Wqb  = ws + 7 * M1;
    us16* Wkb  = ws + 8 * M1;
    us16* Wvb  = ws + 9 * M1;
    us16* qb   = ws + 10 * M1;   // 4M els each
    us16* kb   = ws + 14 * M1;
    us16* vb   = ws + 18 * M1;
    us16* qhb  = ws + 22 * M1;   // [B,H,S,HD]
    us16* khb  = ws + 26 * M1;
    us16* vtb  = ws + 30 * M1;   // [B,H,HD,S]
    us16* xb   = vb;             // vb dead after proj_all
    float* bcq   = (float*)(ws + 34 * M1);
    float* bck   = bcq + 1024;
    float* bcv   = bck + 1024;
    float* zbias = bcv + 1024;
    unsigned long long* mbits = (unsigned long long*)(ws + 34 * M1 + 16384);  // 1 MiB

    prep<<<12852, 256, 0, stream>>>(q, k, v, Wq, Wk, Wv, Whq, Whk, Whv, Wo,
                                    bq, bk, bv, bhq, bhk, bhv, mask,
                                    qb, kb, vb, Wqb, Wkb, Wvb,
                                    WhqT, WhkT, WhvT, WoT, mbits,
                                    bcq, bck, bcv, zbias);

    // combined weights WcT[c][e] = sum_j Wh[h][j][d]*W[e][j] (Q pre-scaled)
    wgemm3<<<dim3(8, 16, 3), 256, 0, stream>>>(WhqT, WhkT, WhvT, Wqb, Wkb, Wvb, zbias,
                                               WcqT, WckT, WcvT);

    // all three projections in one 768-block dispatch
    proj_all<<<768, 256, 0, stream>>>(qb, kb, vb, WcqT, WckT, WcvT,
                                      bcq, bck, bcv, qhb, khb, vtb);

    // full-S flash attention, finalizes x in-kernel (no combine dispatch)
    attn_kernel<<<512, 512, 0, stream>>>(qhb, khb, vtb, mbits, xb);

    // output projection, f32 out
    gemm_out64<<<dim3(8, 64), 256, 0, stream>>>(xb, WoT, bo, (float*)d_out,
                                                M_ROWS, E_DIM, E_DIM);
}

// Round 9
// 303.760 us; speedup vs baseline: 1.1293x; 1.0213x over previous
//
#include <hip/hip_runtime.h>
#include <hip/hip_bf16.h>

typedef unsigned short us16;
typedef __attribute__((ext_vector_type(8))) short short8;   // 8 bf16 in 4 VGPRs
typedef __attribute__((ext_vector_type(4))) float float4v;  // MFMA C/D

#define E_DIM 1024
#define S_LEN 2048
#define B_DIM 2
#define H_DIM 16
#define HD_DIM 64
#define M_ROWS 4096
#define SCALE2 0.18033688011112042f  // (1/8) * log2(e), folded into Wcq/bcq

__device__ __forceinline__ float b2f(us16 b) {
    return __uint_as_float(((unsigned int)b) << 16);
}
__device__ __forceinline__ us16 f2b(float f) {           // RNE
    unsigned int u = __float_as_uint(f);
    unsigned int r = (u + 0x7fffu + ((u >> 16) & 1u)) >> 16;
    return (us16)r;
}

// async global->LDS, 16B/lane; lds base wave-uniform (HW adds lane*16)
__device__ __forceinline__ void gload16(const us16* g, us16* lds_uniform_base) {
    __builtin_amdgcn_global_load_lds(
        (const __attribute__((address_space(1))) void*)g,
        (__attribute__((address_space(3))) void*)lds_uniform_base, 16, 0, 0);
}

// ---------------------------------------------------------------------------
// prep: ALL preprocessing in one dispatch (12852 blocks x 256 thr).
// Mask -> marr bias pass: 1024 INDEPENDENT single-pass blocks (one per
// (b,q0t,kt) window), 128B/thread coalesced reads -> LDS -> 64B/thread
// coalesced writes. (Round-7 version had the same mapping but 4x serial
// iterations in 256 blocks -> occupancy-tail regression; this keeps its
// verified emit mapping with full parallelism.)
// ---------------------------------------------------------------------------
__global__ __launch_bounds__(256) void prep(
    const float* __restrict__ q, const float* __restrict__ k, const float* __restrict__ v,
    const float* __restrict__ Wq, const float* __restrict__ Wk, const float* __restrict__ Wv,
    const float* __restrict__ Whq, const float* __restrict__ Whk, const float* __restrict__ Whv,
    const float* __restrict__ Wo,
    const float* __restrict__ bq, const float* __restrict__ bk, const float* __restrict__ bv,
    const float* __restrict__ bhq, const float* __restrict__ bhk, const float* __restrict__ bhv,
    const int* __restrict__ mask,
    us16* qb, us16* kb, us16* vb, us16* Wqb, us16* Wkb, us16* Wvb,
    us16* WhqT, us16* WhkT, us16* WhvT, us16* WoT,
    us16* marr,
    float* bcq, float* bck, float* bcv, float* zbias)
{
    __shared__ us16 tile[32][33];
    __shared__ float red[4][64];
    __shared__ us16 Lm[128][72];     // mask window (bf16 bias), padded rows
    int blk = blockIdx.x, tid = threadIdx.x;

    if (blk < 7680) {            // f32 -> bf16 streaming converts
        const float* in; us16* out; int idx;
        if (blk < 6144) {
            int z = blk >> 11, rem = blk & 2047;
            in = z == 0 ? q : z == 1 ? k : v;
            out = z == 0 ? qb : z == 1 ? kb : vb;
            idx = (rem * 256 + tid) * 8;
        } else {
            int t = blk - 6144, z = t >> 9, rem = t & 511;
            in = z == 0 ? Wq : z == 1 ? Wk : Wv;
            out = z == 0 ? Wqb : z == 1 ? Wkb : Wvb;
            idx = (rem * 256 + tid) * 8;
        }
        float4 f0 = *(const float4*)(in + idx);
        float4 f1 = *(const float4*)(in + idx + 4);
        us16 t8[8] = {f2b(f0.x), f2b(f0.y), f2b(f0.z), f2b(f0.w),
                      f2b(f1.x), f2b(f1.y), f2b(f1.z), f2b(f1.w)};
        *(uint4*)(out + idx) = *(const uint4*)t8;
    } else if (blk < 11776) {    // weight transposes
        int t = blk - 7680, z = t >> 10, rem = t & 1023;
        const float* in = z == 0 ? Whq : z == 1 ? Whk : z == 2 ? Whv : Wo;
        us16* out = z == 0 ? WhqT : z == 1 ? WhkT : z == 2 ? WhvT : WoT;
        int mode = (z < 3) ? 1 : 0;
        int bx = rem & 31, by = rem >> 5;
        int tx = tid & 31, ty = tid >> 5;
#pragma unroll
        for (int i = 0; i < 4; ++i) {
            int e = by * 32 + ty + i * 8;
            int c = bx * 32 + tx;
            size_t src;
            if (mode == 0) src = (size_t)e * E_DIM + c;
            else           src = ((size_t)(c >> 6) * E_DIM + e) * 64 + (c & 63);
            tile[ty + i * 8][tx] = f2b(in[src]);
        }
        __syncthreads();
#pragma unroll
        for (int i = 0; i < 4; ++i) {
            int c = bx * 32 + ty + i * 8;
            int e = by * 32 + tx;
            out[(size_t)c * E_DIM + e] = tile[tx][ty + i * 8];
        }
    } else if (blk < 12800) {    // mask -> additive-bias bf16 (coalesced, 1 pass)
        // block = (bb, q0t, kt); output record layout UNCHANGED vs round 6:
        // [b][kt:32][q0t:16][w:8][ld:2][lane:64][el:8]
        int t2 = blk - 11776;            // 0..1023
        int kt = t2 & 31, q0t2 = (t2 >> 5) & 15, bb = t2 >> 9;
        const us16 NEGB = f2b(-1e38f);
        // stage: thread -> (row = tid>>1, half = tid&1), 32 consecutive ints
        {
            int row = tid >> 1, half = tid & 1;
            const int* mp = mask + ((size_t)bb * S_LEN + q0t2 * 128 + row) * S_LEN
                            + kt * 64 + half * 32;
            us16 tmp[32];
#pragma unroll
            for (int gi = 0; gi < 8; ++gi) {
                int4 mv = *(const int4*)(mp + gi * 4);
                tmp[gi * 4 + 0] = mv.x ? NEGB : (us16)0;
                tmp[gi * 4 + 1] = mv.y ? NEGB : (us16)0;
                tmp[gi * 4 + 2] = mv.z ? NEGB : (us16)0;
                tmp[gi * 4 + 3] = mv.w ? NEGB : (us16)0;
            }
#pragma unroll
            for (int gi = 0; gi < 4; ++gi)
                *(uint4*)&Lm[row][half * 32 + gi * 8] = *(const uint4*)&tmp[gi * 8];
        }
        __syncthreads();
        // emit (round-7-verified mapping): thread -> (w=tid>>5, ld=(tid>>4)&1, 4 lanes)
        {
            int wv2 = tid >> 5, ld2 = (tid >> 4) & 1, lb = (tid & 15) * 4;
            us16 obuf[32];
#pragma unroll
            for (int li = 0; li < 4; ++li) {
                int lane2 = lb + li;
                int row = wv2 * 16 + (lane2 & 15);
                int tb = ld2 * 32 + (lane2 >> 4) * 4;
                *(uint2*)&obuf[li * 8]     = *(const uint2*)&Lm[row][tb];
                *(uint2*)&obuf[li * 8 + 4] = *(const uint2*)&Lm[row][tb + 16];
            }
            size_t gbase = (((size_t)(bb * 32 + kt) * 16 + q0t2) * 8192) + (size_t)tid * 32;
#pragma unroll
            for (int gi = 0; gi < 4; ++gi)
                *(uint4*)&marr[gbase + gi * 8] = *(const uint4*)&obuf[gi * 8];
        }
    } else if (blk < 12848) {    // combined bias (Q-bias pre-scaled by SCALE2)
        int t = blk - 12800, z = t >> 4, h = t & 15;
        const float* bg = z == 0 ? bq : z == 1 ? bk : bv;
        const float* Wh = z == 0 ? Whq : z == 1 ? Whk : Whv;
        const float* bh = z == 0 ? bhq : z == 1 ? bhk : bhv;
        float* bc = z == 0 ? bcq : z == 1 ? bck : bcv;
        float sc = (z == 0) ? SCALE2 : 1.0f;
        int d = tid & 63, part = tid >> 6;
        float acc = 0.f;
        int j0 = part * 256;
        for (int j = j0; j < j0 + 256; ++j)
            acc += bg[j] * Wh[((size_t)h * E_DIM + j) * HD_DIM + d];
        red[part][d] = acc;
        __syncthreads();
        if (tid < 64)
            bc[h * 64 + tid] = (red[0][tid] + red[1][tid] + red[2][tid] + red[3][tid] + bh[h * 64 + tid]) * sc;
    } else {                     // zero zbias (4 blocks)
        int i = (blk - 12848) * 256 + tid;
        if (i < 1024) zbias[i] = 0.f;
    }
}

// ---------------------------------------------------------------------------
// GEMM body, 128x128x32 tile (big batched projections).
// omode 1: bf16 [B,H,S,HD] (bias[col]); 3: bf16 [B,H,HD,S] (bias[row]).
// ---------------------------------------------------------------------------
#define BK 32

__device__ __forceinline__ void gemm_body(
    const us16* __restrict__ A, const us16* __restrict__ Bt,
    const float* __restrict__ bias, void* __restrict__ Cp,
    int M, int N, int K, int bxt, int byt, int omode)
{
    __shared__ us16 As[128 * BK];
    __shared__ us16 Bs[128 * BK];

    int tid = threadIdx.x;
    int wave = tid >> 6, lane = tid & 63;
    int quad = lane >> 4, l16 = lane & 15;
    int wm = (wave >> 1) * 64, wn = (wave & 1) * 64;
    int bm0 = byt * 128, bn0 = bxt * 128;
    int srow = lane >> 2;
    int gcol = (((lane & 3) ^ (srow & 3)) << 3);
    int rslot = ((quad ^ (l16 & 3)) << 3);

    float4v acc[4][4];
#pragma unroll
    for (int i = 0; i < 4; ++i)
#pragma unroll
        for (int j = 0; j < 4; ++j)
#pragma unroll
            for (int r = 0; r < 4; ++r) acc[i][j][r] = 0.f;

    for (int k0 = 0; k0 < K; k0 += BK) {
#pragma unroll
        for (int c = 0; c < 2; ++c) {
            int r0 = 32 * wave + 16 * c;
            gload16(A  + (size_t)(bm0 + r0 + srow) * K + k0 + gcol, &As[r0 * BK]);
            gload16(Bt + (size_t)(bn0 + r0 + srow) * K + k0 + gcol, &Bs[r0 * BK]);
        }
        __syncthreads();
        short8 af[4], bfr[4];
#pragma unroll
        for (int i = 0; i < 4; ++i)
            af[i] = *(const short8*)&As[(wm + i * 16 + l16) * BK + rslot];
#pragma unroll
        for (int j = 0; j < 4; ++j)
            bfr[j] = *(const short8*)&Bs[(wn + j * 16 + l16) * BK + rslot];
#pragma unroll
        for (int i = 0; i < 4; ++i)
#pragma unroll
            for (int j = 0; j < 4; ++j)
                acc[i][j] = __builtin_amdgcn_mfma_f32_16x16x32_bf16(af[i], bfr[j], acc[i][j], 0, 0, 0);
        __syncthreads();
    }

#pragma unroll
    for (int i = 0; i < 4; ++i) {
#pragma unroll
        for (int j = 0; j < 4; ++j) {
#pragma unroll
            for (int r = 0; r < 4; ++r) {
                int row = bm0 + wm + i * 16 + quad * 4 + r;
                int col = bn0 + wn + j * 16 + l16;
                float vv = acc[i][j][r] + ((omode == 3) ? bias[row] : bias[col]);
                if (omode == 1) {
                    int b = row >> 11, s = row & 2047, h = col >> 6, d = col & 63;
                    ((us16*)Cp)[(((size_t)(b * H_DIM + h) * S_LEN + s) * HD_DIM) + d] = f2b(vv);
                } else {  // 3: row=c (h*64+d), col=b*2048+s -> [B,H,HD,S]
                    int h = row >> 6, d = row & 63, b = col >> 11, sl = col & 2047;
                    ((us16*)Cp)[(((size_t)(b * H_DIM + h) * HD_DIM + d) * S_LEN) + sl] = f2b(vv);
                }
            }
        }
    }
}

// all three fused projections in ONE 768-block dispatch (3 blocks/CU)
__global__ __launch_bounds__(256) void proj_all(
    const us16* __restrict__ qb, const us16* __restrict__ kb, const us16* __restrict__ vb,
    const us16* __restrict__ WcqT, const us16* __restrict__ WckT, const us16* __restrict__ WcvT,
    const float* __restrict__ bcq, const float* __restrict__ bck, const float* __restrict__ bcv,
    us16* __restrict__ qhb, us16* __restrict__ khb, us16* __restrict__ vtb)
{
    int bx = blockIdx.x;
    int z = bx >> 8, t = bx & 255;
    if (z == 0)      gemm_body(qb, WcqT, bcq, qhb, M_ROWS, E_DIM, E_DIM, t & 7, t >> 3, 1);
    else if (z == 1) gemm_body(kb, WckT, bck, khb, M_ROWS, E_DIM, E_DIM, t & 7, t >> 3, 1);
    else             gemm_body(WcvT, vb, bcv, vtb, E_DIM, M_ROWS, E_DIM, t & 31, t >> 5, 3);
}

// ---------------------------------------------------------------------------
// 64x128-tile GEMM body. OMODE 0: bf16 [M,N]; 2: f32 [M,N]. bias[col], *oscale.
// ---------------------------------------------------------------------------
template<int OMODE>
__device__ __forceinline__ void gemm64_body(
    const us16* __restrict__ A, const us16* __restrict__ Bt,
    const float* __restrict__ bias, void* __restrict__ Cp,
    int M, int N, int K, int bxt, int byt, float oscale)
{
    __shared__ us16 As[64 * BK];
    __shared__ us16 Bs[128 * BK];

    int tid = threadIdx.x;
    int wave = tid >> 6, lane = tid & 63;
    int quad = lane >> 4, l16 = lane & 15;
    int wm = (wave >> 1) * 32, wn = (wave & 1) * 64;
    int bm0 = byt * 64, bn0 = bxt * 128;
    int srow = lane >> 2;
    int gcol = (((lane & 3) ^ (srow & 3)) << 3);
    int rslot = ((quad ^ (l16 & 3)) << 3);

    float4v acc[2][4];
#pragma unroll
    for (int i = 0; i < 2; ++i)
#pragma unroll
        for (int j = 0; j < 4; ++j)
#pragma unroll
            for (int r = 0; r < 4; ++r) acc[i][j][r] = 0.f;

    for (int k0 = 0; k0 < K; k0 += BK) {
        gload16(A + (size_t)(bm0 + 16 * wave + srow) * K + k0 + gcol, &As[16 * wave * BK]);
#pragma unroll
        for (int c = 0; c < 2; ++c) {
            int r0 = 32 * wave + 16 * c;
            gload16(Bt + (size_t)(bn0 + r0 + srow) * K + k0 + gcol, &Bs[r0 * BK]);
        }
        __syncthreads();
        short8 af[2], bfr[4];
#pragma unroll
        for (int i = 0; i < 2; ++i)
            af[i] = *(const short8*)&As[(wm + i * 16 + l16) * BK + rslot];
#pragma unroll
        for (int j = 0; j < 4; ++j)
            bfr[j] = *(const short8*)&Bs[(wn + j * 16 + l16) * BK + rslot];
#pragma unroll
        for (int i = 0; i < 2; ++i)
#pragma unroll
            for (int j = 0; j < 4; ++j)
                acc[i][j] = __builtin_amdgcn_mfma_f32_16x16x32_bf16(af[i], bfr[j], acc[i][j], 0, 0, 0);
        __syncthreads();
    }

#pragma unroll
    for (int i = 0; i < 2; ++i)
#pragma unroll
        for (int j = 0; j < 4; ++j)
#pragma unroll
            for (int r = 0; r < 4; ++r) {
                int row = bm0 + wm + i * 16 + quad * 4 + r;
                int col = bn0 + wn + j * 16 + l16;
                float vv = (acc[i][j][r] + bias[col]) * oscale;
                if (OMODE == 0) ((us16*)Cp)[(size_t)row * N + col] = f2b(vv);
                else            ((float*)Cp)[(size_t)row * N + col] = vv;
            }
}

// batched weight-combine: C_z = WhT_z @ Wb_z^T; z==0 output pre-scaled SCALE2
__global__ __launch_bounds__(256) void wgemm3(
    const us16* A0, const us16* A1, const us16* A2,
    const us16* B0, const us16* B1, const us16* B2,
    const float* zbias, us16* C0, us16* C1, us16* C2)
{
    int z = blockIdx.z;
    const us16* A = z == 0 ? A0 : z == 1 ? A1 : A2;
    const us16* Bt = z == 0 ? B0 : z == 1 ? B1 : B2;
    us16* C = z == 0 ? C0 : z == 1 ? C1 : C2;
    float sc = (z == 0) ? SCALE2 : 1.0f;
    gemm64_body<0>(A, Bt, zbias, C, E_DIM, E_DIM, E_DIM, blockIdx.x, blockIdx.y, sc);
}

// out projection: f32 out, grid (8,64)=512 blocks
__global__ __launch_bounds__(256) void gemm_out64(
    const us16* __restrict__ A, const us16* __restrict__ Bt,
    const float* __restrict__ bias, float* __restrict__ C, int M, int N, int K)
{
    gemm64_body<2>(A, Bt, bias, C, M, N, K, blockIdx.x, blockIdx.y, 1.0f);
}

// ---------------------------------------------------------------------------
// Flash attention, S^T formulation (fixed-max softmax; scores pre-scaled via
// Wcq). Mask = bf16 additive bias (marr) as MFMA C-init; P via cvt_pk; l via
// ones-MFMA. Depth-2 pipeline with COUNTED vmcnt (T3/T4): per tile
//   SM(t) -> PV(t) -> barrier -> issue DMA(t+2) -> vmcnt(2) -> barrier
//   -> QK(t+1)
// FULL-S per block (no K-split): block = (bh, q0t), NT=32 K-tiles; O is
// finalized in-kernel (divide by l) and written straight to x -- no partials,
// no combine dispatch. Grid 512 blocks = exactly 2/CU, all co-resident.
// XCD-aware 1-D grid (4 heads/XCD). 512 thr = 8 waves, Q-tile 128.
// ---------------------------------------------------------------------------
#define PST 72   // Pw row stride (els)
#define NT 32    // K-tiles per block (64 wide, full S)

__global__ __launch_bounds__(512) void attn_kernel(
    const us16* __restrict__ qh, const us16* __restrict__ kh,
    const us16* __restrict__ vt, const us16* __restrict__ marr,
    us16* __restrict__ x)
{
    __shared__ us16 Ks[2][64 * 64];   // packed, swizzled: slot c holds chunk c^(t&7)
    __shared__ us16 Vs[2][64 * 64];
    __shared__ us16 Pw[8][16 * PST];

    int tid = threadIdx.x;
    int w = tid >> 6, lane = tid & 63;
    int quad = lane >> 4, l16 = lane & 15;

    // XCD-aware decode: 4 heads per XCD so K/V panels stay L2-resident.
    int wg = blockIdx.x;                 // 0..511
    int xcd = wg & 7, idx = wg >> 3;     // 64 blocks per XCD
    int bh = xcd * 4 + (idx >> 4);       // 4 bh per XCD
    int q0t = idx & 15;
    int q0 = q0t * 128;
    int b = bh >> 4;
    const size_t base = (size_t)bh * (S_LEN * HD_DIM);

    int qrow = q0 + w * 16 + l16;
    short8 qf0, qf1;
    {
        const us16* qp = qh + base + (size_t)qrow * HD_DIM + quad * 8;
        qf0 = *(const short8*)qp;
        qf1 = *(const short8*)(qp + 32);
    }

    // ones B-fragment for l = P x 1 (all bf16 1.0)
    short8 onesf;
#pragma unroll
    for (int j = 0; j < 8; ++j) onesf[j] = (short)0x3F80;

    // staging geometry: wave w stages rows w*8..w*8+7; slot c <- chunk c^(row&7)
    int strow = w * 8 + (lane >> 3);
    int scol = ((lane & 7) ^ (strow & 7)) * 8;
    const us16* ksrc0 = kh + base + (size_t)strow * HD_DIM + scol;
    const us16* vsrc0 = vt + base + (size_t)strow * S_LEN + scol;

    // mask-bias base: [b][kt:32][q0t:16][w:8][ld:2][lane:64][el:8]
    const us16* mb0p = marr + ((((size_t)(b * 32) * 16 + q0t) * 8 + w) * 1024)
                            + (size_t)lane * 8;

    // frag-read slots
    int slotA = (quad ^ (l16 & 7)) * 8;     // chunk quad
    int slotB = slotA ^ 32;                 // chunk quad+4

    float4v o[4];
#pragma unroll
    for (int dt = 0; dt < 4; ++dt)
#pragma unroll
        for (int r = 0; r < 4; ++r) o[dt][r] = 0.f;
    float4v o_l;
#pragma unroll
    for (int r = 0; r < 4; ++r) o_l[r] = 0.f;

    // QK for tile in KsC with mask C-init (m0,m1) -> sc[4]
    auto QK = [&](const us16* KsC, uint4 m0, uint4 m1, float4v* sc) {
        __builtin_amdgcn_s_setprio(1);
#pragma unroll
        for (int ct = 0; ct < 4; ++ct) {
            int tt = ct * 16 + l16;
            short8 kf0 = *(const short8*)&KsC[tt * 64 + slotA];
            short8 kf1 = *(const short8*)&KsC[tt * 64 + slotB];
            unsigned w0, w1;
            if (ct == 0)      { w0 = m0.x; w1 = m0.y; }
            else if (ct == 1) { w0 = m0.z; w1 = m0.w; }
            else if (ct == 2) { w0 = m1.x; w1 = m1.y; }
            else              { w0 = m1.z; w1 = m1.w; }
            float4v a;
            a[0] = __uint_as_float(w0 << 16);
            a[1] = __uint_as_float(w0 & 0xFFFF0000u);
            a[2] = __uint_as_float(w1 << 16);
            a[3] = __uint_as_float(w1 & 0xFFFF0000u);
            a = __builtin_amdgcn_mfma_f32_16x16x32_bf16(kf0, qf0, a, 0, 0, 0);
            a = __builtin_amdgcn_mfma_f32_16x16x32_bf16(kf1, qf1, a, 0, 0, 0);
            sc[ct] = a;
        }
        __builtin_amdgcn_s_setprio(0);
    };

    // prologue: stage tiles 0 and 1; mask(0); wait tile 0 only; QK(0)
    gload16(ksrc0, &Ks[0][w * 512]);
    gload16(vsrc0, &Vs[0][w * 512]);
    gload16(ksrc0 + (size_t)64 * HD_DIM, &Ks[1][w * 512]);
    gload16(vsrc0 + 64, &Vs[1][w * 512]);
    uint4 mc0 = *(const uint4*)(mb0p);
    uint4 mc1 = *(const uint4*)(mb0p + 512);
    asm volatile("s_waitcnt vmcnt(2)" ::: "memory");
    __builtin_amdgcn_s_barrier();
    __builtin_amdgcn_sched_barrier(0);

    float4v sc[4];
    QK(Ks[0], mc0, mc1, sc);

    for (int t = 0; t < NT; ++t) {
        int cur = t & 1;

        // mask(t+1) load early (hides under SM+PV)
        uint4 mn0 = mc0, mn1 = mc1;
        if (t + 1 < NT) {
            const us16* mp = mb0p + (size_t)(t + 1) * 131072;
            mn0 = *(const uint4*)(mp);
            mn1 = *(const uint4*)(mp + 512);
        }

        // SM(t): exp2 + cvt_pk pack + b64 write (scores pre-scaled via Wcq)
#pragma unroll
        for (int ct = 0; ct < 4; ++ct) {
            float p0 = __builtin_amdgcn_exp2f(sc[ct][0]);
            float p1 = __builtin_amdgcn_exp2f(sc[ct][1]);
            float p2 = __builtin_amdgcn_exp2f(sc[ct][2]);
            float p3 = __builtin_amdgcn_exp2f(sc[ct][3]);
            uint2 pk;
            asm("v_cvt_pk_bf16_f32 %0, %1, %2" : "=v"(pk.x) : "v"(p0), "v"(p1));
            asm("v_cvt_pk_bf16_f32 %0, %1, %2" : "=v"(pk.y) : "v"(p2), "v"(p3));
            *(uint2*)&Pw[w][l16 * PST + ct * 16 + quad * 4] = pk;
        }

        // PV(t): O += P.V ; l += P.1 (ones-MFMA)
        short8 pf0 = *(const short8*)&Pw[w][l16 * PST + quad * 8];
        short8 pf1 = *(const short8*)&Pw[w][l16 * PST + 32 + quad * 8];
        const us16* VsC = Vs[cur];
        __builtin_amdgcn_s_setprio(1);
#pragma unroll
        for (int dt = 0; dt < 4; ++dt) {
            int d = dt * 16 + l16;
            short8 vf0 = *(const short8*)&VsC[d * 64 + slotA];
            short8 vf1 = *(const short8*)&VsC[d * 64 + slotB];
            o[dt] = __builtin_amdgcn_mfma_f32_16x16x32_bf16(pf0, vf0, o[dt], 0, 0, 0);
            o[dt] = __builtin_amdgcn_mfma_f32_16x16x32_bf16(pf1, vf1, o[dt], 0, 0, 0);
        }
        o_l = __builtin_amdgcn_mfma_f32_16x16x32_bf16(pf0, onesf, o_l, 0, 0, 0);
        o_l = __builtin_amdgcn_mfma_f32_16x16x32_bf16(pf1, onesf, o_l, 0, 0, 0);
        __builtin_amdgcn_s_setprio(0);

        if (t + 1 == NT) break;

        // all waves done reading buf[cur] -> safe to overwrite
        __builtin_amdgcn_s_barrier();
        __builtin_amdgcn_sched_barrier(0);

        if (t + 2 < NT) {
            gload16(ksrc0 + (size_t)((t + 2) * 64) * HD_DIM, &Ks[cur][w * 512]);
            gload16(vsrc0 + (t + 2) * 64, &Vs[cur][w * 512]);
            // outstanding: DMA(t+1)=2 + DMA(t+2)=2; wait until only t+2 remains
            asm volatile("s_waitcnt vmcnt(2)" ::: "memory");
        } else {
            // nothing more to issue; drain DMA(t+1)
            asm volatile("s_waitcnt vmcnt(0)" ::: "memory");
        }
        __builtin_amdgcn_s_barrier();
        __builtin_amdgcn_sched_barrier(0);

        // QK(t+1) from the freshly-ready buffer
        mc0 = mn0; mc1 = mn1;
        QK(Ks[cur ^ 1], mc0, mc1, sc);
    }

    // finalize: divide by l (o_l[r] = row-sum, equal across l16) and write x
    float linv[4];
#pragma unroll
    for (int r = 0; r < 4; ++r) linv[r] = 1.0f / o_l[r];
    int h = bh & 15;
    int srow0 = q0 + w * 16 + quad * 4;
#pragma unroll
    for (int r = 0; r < 4; ++r) {
        size_t xro = ((size_t)(b * S_LEN + srow0 + r)) * E_DIM + h * HD_DIM;
#pragma unroll
        for (int dt = 0; dt < 4; ++dt)
            x[xro + dt * 16 + l16] = f2b(o[dt][r] * linv[r]);
    }
}

// ---------------------------------------------------------------------------
extern "C" void kernel_launch(void* const* d_in, const int* in_sizes, int n_in,
                              void* d_out, int out_size, void* d_ws, size_t ws_size,
                              hipStream_t stream) {
    const float* q    = (const float*)d_in[0];
    const float* k    = (const float*)d_in[1];
    const float* v    = (const float*)d_in[2];
    const int*   mask = (const int*)d_in[3];
    const float* Wq = (const float*)d_in[4];   const float* bq = (const float*)d_in[5];
    const float* Wk = (const float*)d_in[6];   const float* bk = (const float*)d_in[7];
    const float* Wv = (const float*)d_in[8];   const float* bv = (const float*)d_in[9];
    const float* Whq = (const float*)d_in[10]; const float* bhq = (const float*)d_in[11];
    const float* Whk = (const float*)d_in[12]; const float* bhk = (const float*)d_in[13];
    const float* Whv = (const float*)d_in[14]; const float* bhv = (const float*)d_in[15];
    const float* Wo = (const float*)d_in[16];  const float* bo = (const float*)d_in[17];

    us16* ws = (us16*)d_ws;
    const size_t M1 = (size_t)1 << 20;  // 1M bf16 elems = 2 MiB
    us16* WhqT = ws + 0 * M1;
    us16* WhkT = ws + 1 * M1;
    us16* WhvT = ws + 2 * M1;
    us16* WoT  = ws + 3 * M1;
    us16* WcqT = ws + 4 * M1;
    us16* WckT = ws + 5 * M1;
    us16* WcvT = ws + 6 * M1;
    us16* Wqb  = ws + 7 * M1;
    us16* Wkb  = ws + 8 * M1;
    us16* Wvb  = ws + 9 * M1;
    us16* qb   = ws + 10 * M1;   // 4M els each
    us16* kb   = ws + 14 * M1;
    us16* vb   = ws + 18 * M1;
    us16* qhb  = ws + 22 * M1;   // [B,H,S,HD]
    us16* khb  = ws + 26 * M1;
    us16* vtb  = ws + 30 * M1;   // [B,H,HD,S]
    us16* xb   = vb;             // vb dead after proj_all
    float* bcq   = (float*)(ws + 34 * M1);
    float* bck   = bcq + 1024;
    float* bcv   = bck + 1024;
    float* zbias = bcv + 1024;
    us16*  marr  = ws + 35 * M1;                         // 8M els = 16 MiB

    prep<<<12852, 256, 0, stream>>>(q, k, v, Wq, Wk, Wv, Whq, Whk, Whv, Wo,
                                    bq, bk, bv, bhq, bhk, bhv, mask,
                                    qb, kb, vb, Wqb, Wkb, Wvb,
                                    WhqT, WhkT, WhvT, WoT, marr,
                                    bcq, bck, bcv, zbias);

    // combined weights WcT[c][e] = sum_j Wh[h][j][d]*W[e][j] (Q pre-scaled)
    wgemm3<<<dim3(8, 16, 3), 256, 0, stream>>>(WhqT, WhkT, WhvT, Wqb, Wkb, Wvb, zbias,
                                               WcqT, WckT, WcvT);

    // all three projections in one 768-block dispatch
    proj_all<<<768, 256, 0, stream>>>(qb, kb, vb, WcqT, WckT, WcvT,
                                      bcq, bck, bcv, qhb, khb, vtb);

    // full-S flash attention, finalizes x in-kernel (no combine dispatch)
    attn_kernel<<<512, 512, 0, stream>>>(qhb, khb, vtb, marr, xb);

    // output projection, f32 out
    gemm_out64<<<dim3(8, 64), 256, 0, stream>>>(xb, WoT, bo, (float*)d_out,
                                                M_ROWS, E_DIM, E_DIM);
}